// Round 7
// baseline (513.387 us; speedup 1.0000x reference)
//
#include <hip/hip_runtime.h>
#include <hip/hip_bf16.h>

#define B_ 4
#define S_ 4096
#define E_ 1024
#define H_ 16
#define D_ 64
#define NS_ 1024
#define M_ (B_*S_)
#define K_ E_
#define DELTA 0.12f
#define BANDCAP 96

typedef __attribute__((ext_vector_type(8))) short bf16x8;
typedef __attribute__((ext_vector_type(4))) float floatx4;
typedef __attribute__((ext_vector_type(2))) float f32x2;

#define THSTEP 0.00038349519697141023f  /* (pi/2)/4096 */

__device__ inline float bf16_to_f(unsigned short u) {
    return __uint_as_float(((unsigned)u) << 16);
}
__device__ inline unsigned short f_to_bf16(float f) {
    unsigned u = __float_as_uint(f);
    unsigned r = (u + 0x7FFFu + ((u >> 16) & 1u)) >> 16;  // RNE
    return (unsigned short)r;
}

// async global->LDS DMA, 16B per lane, wave-uniform LDS base + lane*16 dest.
__device__ inline void gl_lds16(const void* g, void* l) {
    __builtin_amdgcn_global_load_lds(
        (const __attribute__((address_space(1))) void*)g,
        (__attribute__((address_space(3))) void*)l, 16, 0, 0);
}

// ---------------------------------------------------------------------------
// Prep kernel: fuses {zero(out), x->xh bf16, W splits}.  4096 blocks x 256.
// ---------------------------------------------------------------------------
__global__ __launch_bounds__(256) void prep_kernel(
    const float* __restrict__ x,
    const float* __restrict__ Wq, const float* __restrict__ Wk,
    const float* __restrict__ Wv,
    ushort* __restrict__ xh,
    ushort* __restrict__ Wqh, ushort* __restrict__ Wql,
    ushort* __restrict__ Wkh, ushort* __restrict__ Wkl,
    ushort* __restrict__ Wvh,
    uint4* __restrict__ outz)
{
    int t = blockIdx.x * 256 + threadIdx.x;     // 0 .. 1,048,575
    uint4 z = make_uint4(0u, 0u, 0u, 0u);
#pragma unroll
    for (int c = 0; c < 4; ++c)
        outz[c * 1048576 + t] = z;               // 4M uint4 = 64MB out
#pragma unroll
    for (int c = 0; c < 4; ++c) {
        int i = c * 1048576 + t;                 // 4M float4 of x
        float4 v = ((const float4*)x)[i];
        ushort4 hh;
        hh.x = f_to_bf16(v.x); hh.y = f_to_bf16(v.y);
        hh.z = f_to_bf16(v.z); hh.w = f_to_bf16(v.w);
        ((ushort4*)xh)[i] = hh;
    }
    if (t < 262144) {                            // 256K float4 per W matrix
        int i = t;
        float4 q = ((const float4*)Wq)[i];
        float4 k = ((const float4*)Wk)[i];
        float4 v = ((const float4*)Wv)[i];
        ushort4 h, l;
        h.x=f_to_bf16(q.x); l.x=f_to_bf16(q.x-bf16_to_f(h.x));
        h.y=f_to_bf16(q.y); l.y=f_to_bf16(q.y-bf16_to_f(h.y));
        h.z=f_to_bf16(q.z); l.z=f_to_bf16(q.z-bf16_to_f(h.z));
        h.w=f_to_bf16(q.w); l.w=f_to_bf16(q.w-bf16_to_f(h.w));
        ((ushort4*)Wqh)[i]=h; ((ushort4*)Wql)[i]=l;
        h.x=f_to_bf16(k.x); l.x=f_to_bf16(k.x-bf16_to_f(h.x));
        h.y=f_to_bf16(k.y); l.y=f_to_bf16(k.y-bf16_to_f(h.y));
        h.z=f_to_bf16(k.z); l.z=f_to_bf16(k.z-bf16_to_f(h.z));
        h.w=f_to_bf16(k.w); l.w=f_to_bf16(k.w-bf16_to_f(h.w));
        ((ushort4*)Wkh)[i]=h; ((ushort4*)Wkl)[i]=l;
        h.x=f_to_bf16(v.x); h.y=f_to_bf16(v.y);
        h.z=f_to_bf16(v.z); h.w=f_to_bf16(v.w);
        ((ushort4*)Wvh)[i]=h;
    }
}

// ---------------------------------------------------------------------------
// Kernel 1: QKV GEMM.  2-phase double-buffered BK=32 (T3-min schedule):
// issue next K-step's global_load_lds BEFORE this step's MFMAs; ONE barrier
// per K-step (was 2).  Same 48KB LDS, bit-identical accumulation order.
// Swizzle for 64B rows: g = c ^ ((r>>1)&3) -> 2-way bank alias (free, m136).
// ---------------------------------------------------------------------------
__global__ __launch_bounds__(256) void qkv_gemm(
    const ushort* __restrict__ xh,
    const ushort* __restrict__ Wqh, const ushort* __restrict__ Wql,
    const ushort* __restrict__ Wkh, const ushort* __restrict__ Wkl,
    const ushort* __restrict__ Wvh,
    const float* __restrict__ bq, const float* __restrict__ bk,
    const float* __restrict__ bv,
    float* __restrict__ q32, float* __restrict__ k32, ushort* __restrict__ v16)
{
    __shared__ __align__(16) ushort As[2][128 * 32];
    __shared__ __align__(16) ushort Bsh[2][128 * 32];
    __shared__ __align__(16) ushort Bsl[2][128 * 32];

    const int w = blockIdx.z;
    const ushort* Bhp = (w == 0) ? Wqh : (w == 1) ? Wkh : Wvh;
    const ushort* Blp = (w == 0) ? Wql : Wkl;      // unused when w==2
    const float* bias = (w == 0) ? bq : (w == 1) ? bk : bv;
    const bool lo = (w < 2);

    const int m0 = blockIdx.x * 128;
    const int n0 = blockIdx.y * 128;
    const int t = threadIdx.x;
    const int wave = t >> 6, lane = t & 63;
    const int wm = (wave >> 1) * 64, wn = (wave & 1) * 64;
    const int m16 = lane & 15, quad = lane >> 4;

    floatx4 acc[4][4];
#pragma unroll
    for (int i = 0; i < 4; i++)
#pragma unroll
        for (int j = 0; j < 4; j++) acc[i][j] = (floatx4){0.f, 0.f, 0.f, 0.f};

    // staging offsets: 512 chunks of 16B per plane, 2 per thread
    int aoff[2], boff[2], lbase[2];
#pragma unroll
    for (int i = 0; i < 2; i++) {
        int slot = i * 256 + t;
        int r = slot >> 2, c = slot & 3, g = c ^ ((r >> 1) & 3);
        aoff[i] = (m0 + r) * K_ + g * 8;
        boff[i] = (n0 + r) * K_ + g * 8;
        lbase[i] = (i * 256 + wave * 64) * 8;   // wave-uniform LDS element base
    }

    // frag read element offsets (per mt/nt row)
    int afo[4], bfo[4];
#pragma unroll
    for (int mt = 0; mt < 4; ++mt) {
        int r = wm + mt * 16 + m16;
        afo[mt] = (r * 4 + (quad ^ ((r >> 1) & 3))) * 8;
        int r2 = wn + mt * 16 + m16;
        bfo[mt] = (r2 * 4 + (quad ^ ((r2 >> 1) & 3))) * 8;
    }

    // prologue: stage K-step 0 into buffer 0
#pragma unroll
    for (int i = 0; i < 2; i++) {
        gl_lds16(xh + aoff[i], &As[0][lbase[i]]);
        gl_lds16(Bhp + boff[i], &Bsh[0][lbase[i]]);
        if (lo) gl_lds16(Blp + boff[i], &Bsl[0][lbase[i]]);
    }
    __syncthreads();

    for (int ks = 0; ks < 32; ++ks) {
        const int cur = ks & 1;
        if (ks < 31) {                 // issue next-step loads BEFORE compute
            const int kcol = (ks + 1) * 32;
#pragma unroll
            for (int i = 0; i < 2; i++) {
                gl_lds16(xh + aoff[i] + kcol, &As[cur ^ 1][lbase[i]]);
                gl_lds16(Bhp + boff[i] + kcol, &Bsh[cur ^ 1][lbase[i]]);
                if (lo) gl_lds16(Blp + boff[i] + kcol, &Bsl[cur ^ 1][lbase[i]]);
            }
        }

        bf16x8 af[4], bfr[4];
#pragma unroll
        for (int mt = 0; mt < 4; ++mt) af[mt] = *(const bf16x8*)&As[cur][afo[mt]];
#pragma unroll
        for (int nt = 0; nt < 4; ++nt) bfr[nt] = *(const bf16x8*)&Bsh[cur][bfo[nt]];
#pragma unroll
        for (int mt = 0; mt < 4; ++mt)
#pragma unroll
            for (int nt = 0; nt < 4; ++nt)
                acc[mt][nt] = __builtin_amdgcn_mfma_f32_16x16x32_bf16(
                    af[mt], bfr[nt], acc[mt][nt], 0, 0, 0);
        if (lo) {
#pragma unroll
            for (int nt = 0; nt < 4; ++nt) bfr[nt] = *(const bf16x8*)&Bsl[cur][bfo[nt]];
#pragma unroll
            for (int mt = 0; mt < 4; ++mt)
#pragma unroll
                for (int nt = 0; nt < 4; ++nt)
                    acc[mt][nt] = __builtin_amdgcn_mfma_f32_16x16x32_bf16(
                        af[mt], bfr[nt], acc[mt][nt], 0, 0, 0);
        }
        __syncthreads();               // drains next-step staging too
    }

    float biasv[4];
#pragma unroll
    for (int nt = 0; nt < 4; nt++)
        biasv[nt] = bias[n0 + wn + nt * 16 + m16];

    if (w < 2) {
        float* dst = (w == 0) ? q32 : k32;
#pragma unroll
        for (int mt = 0; mt < 4; ++mt)
#pragma unroll
            for (int nt = 0; nt < 4; ++nt) {
                int colg = n0 + wn + nt * 16 + m16;
#pragma unroll
                for (int reg = 0; reg < 4; ++reg) {
                    int rowg = m0 + wm + mt * 16 + quad * 4 + reg;
                    dst[(size_t)rowg * E_ + colg] = acc[mt][nt][reg] + biasv[nt];
                }
            }
    } else {
#pragma unroll
        for (int mt = 0; mt < 4; ++mt)
#pragma unroll
            for (int nt = 0; nt < 4; ++nt) {
                int colg = n0 + wn + nt * 16 + m16;
#pragma unroll
                for (int reg = 0; reg < 4; ++reg) {
                    int rowg = m0 + wm + mt * 16 + quad * 4 + reg;
                    v16[(size_t)rowg * E_ + colg] = f_to_bf16(acc[mt][nt][reg] + biasv[nt]);
                }
            }
    }
}

// ---------------------------------------------------------------------------
// Fat kernel L1: kv_mfma (blocks 0..1023, MFMA/VALU-bound) overlapped with
// scores (blocks 1024..17407, BW-bound, 16 tokens/block).  R7 FIX: scores
// needs 16384 blocks (B*H*S/16), not 4096 — undercount left 3/4 of scores
// uninitialized -> garbage indices -> page fault.
// ---------------------------------------------------------------------------
__global__ __launch_bounds__(256) void scores_kv_kernel(
    const float* __restrict__ q32, const float* __restrict__ k32,
    const ushort* __restrict__ v16,
    float* __restrict__ scores, float* __restrict__ kvp)
{
    // planes: 0 kc_hi, 1 kc_lo, 2 ks_hi, 3 ks_lo, 4 v   (each [64][88] ushort)
    __shared__ __align__(16) ushort P[5 * 64 * 88];
    const int t = threadIdx.x;

    if (blockIdx.x >= 1024) {
        // ---------------- scores: sum_d q*k, one token per 16-lane group ----
        int g = (blockIdx.x - 1024) * 16 + (t >> 4);
        int sub = t & 15;
        int s = g & (S_ - 1);
        int bh = g >> 12;
        int b = bh >> 4, h = bh & 15;
        size_t addr = (size_t)(b * S_ + s) * E_ + h * 64 + sub * 4;
        float4 qv = *(const float4*)(q32 + addr);
        float4 kv = *(const float4*)(k32 + addr);
        float p = qv.x * kv.x + qv.y * kv.y + qv.z * kv.z + qv.w * kv.w;
#pragma unroll
        for (int m = 8; m; m >>= 1) p += __shfl_xor(p, m, 64);
        if (sub == 0) scores[g] = p;
        return;
    }

    // ---------------- kv_mfma (R4-proven body) -----------------------------
    const int ch = blockIdx.x & 15;
    const int bh = blockIdx.x >> 4;
    const int b = bh >> 4, h = bh & 15;
    const int wave = t >> 6, lane = t & 63;
    const int m16 = lane & 15, quad = lane >> 4;
    const int wm = (wave >> 1) * 32, wn = (wave & 1) * 32;
    const int d0 = wave * 16;

    const float*  kbase = k32 + (size_t)b * S_ * E_ + h * 64 + d0;
    const ushort* vbase = v16 + (size_t)b * S_ * E_ + h * 64 + d0;

    floatx4 acc[2][2][2];
#pragma unroll
    for (int p = 0; p < 2; p++)
#pragma unroll
        for (int i = 0; i < 2; i++)
#pragma unroll
            for (int j = 0; j < 2; j++) acc[p][i][j] = (floatx4){0.f,0.f,0.f,0.f};

    float  ka[16];
    ushort va[16];
    int sg = ch * 256 + lane;
    {
        const float*  kr = kbase + (size_t)sg * E_;
        const ushort* vr = vbase + (size_t)sg * E_;
#pragma unroll
        for (int j = 0; j < 4; ++j) *(float4*)&ka[j * 4] = ((const float4*)kr)[j];
        *(uint4*)&va[0] = *(const uint4*)vr;
        *(uint4*)&va[8] = *(const uint4*)(vr + 8);
    }

    for (int grp = 0; grp < 4; ++grp) {
        float th = (float)sg * THSTEP;
        float cw = __cosf(th), sw = __sinf(th);
        int s_loc = lane;

        __syncthreads();
#pragma unroll
        for (int j = 0; j < 16; ++j) {
            float kr_ = fmaxf(ka[j], 0.f);
            float pc = kr_ * cw, ps = kr_ * sw;
            ushort chh = f_to_bf16(pc);
            ushort cll = f_to_bf16(pc - bf16_to_f(chh));
            ushort shh = f_to_bf16(ps);
            ushort sll = f_to_bf16(ps - bf16_to_f(shh));
            int r = (d0 + j) * 88 + s_loc;
            P[0 * 5632 + r] = chh;
            P[1 * 5632 + r] = cll;
            P[2 * 5632 + r] = shh;
            P[3 * 5632 + r] = sll;
            P[4 * 5632 + r] = va[j];
        }
        __syncthreads();

        if (grp < 3) {
            sg += 64;
            const float*  kr = kbase + (size_t)sg * E_;
            const ushort* vr = vbase + (size_t)sg * E_;
#pragma unroll
            for (int j = 0; j < 4; ++j) *(float4*)&ka[j * 4] = ((const float4*)kr)[j];
            *(uint4*)&va[0] = *(const uint4*)vr;
            *(uint4*)&va[8] = *(const uint4*)(vr + 8);
        }

#pragma unroll
        for (int kk = 0; kk < 2; ++kk) {
            const int so = kk * 32 + quad * 8;
            bf16x8 ach[2], acl[2], ash[2], asl[2], bv[2];
#pragma unroll
            for (int mt = 0; mt < 2; ++mt) {
                int r = (wm + mt * 16 + m16) * 88 + so;
                ach[mt] = *(const bf16x8*)&P[0 * 5632 + r];
                acl[mt] = *(const bf16x8*)&P[1 * 5632 + r];
                ash[mt] = *(const bf16x8*)&P[2 * 5632 + r];
                asl[mt] = *(const bf16x8*)&P[3 * 5632 + r];
            }
#pragma unroll
            for (int nt = 0; nt < 2; ++nt) {
                int r = (wn + nt * 16 + m16) * 88 + so;
                bv[nt] = *(const bf16x8*)&P[4 * 5632 + r];
            }
#pragma unroll
            for (int mt = 0; mt < 2; ++mt)
#pragma unroll
                for (int nt = 0; nt < 2; ++nt) {
                    acc[0][mt][nt] = __builtin_amdgcn_mfma_f32_16x16x32_bf16(
                        ach[mt], bv[nt], acc[0][mt][nt], 0, 0, 0);
                    acc[0][mt][nt] = __builtin_amdgcn_mfma_f32_16x16x32_bf16(
                        acl[mt], bv[nt], acc[0][mt][nt], 0, 0, 0);
                    acc[1][mt][nt] = __builtin_amdgcn_mfma_f32_16x16x32_bf16(
                        ash[mt], bv[nt], acc[1][mt][nt], 0, 0, 0);
                    acc[1][mt][nt] = __builtin_amdgcn_mfma_f32_16x16x32_bf16(
                        asl[mt], bv[nt], acc[1][mt][nt], 0, 0, 0);
                }
        }
    }

    float* base = kvp + ((size_t)(bh * 16 + ch) * 2) * 4096;
#pragma unroll
    for (int p = 0; p < 2; ++p)
#pragma unroll
        for (int mt = 0; mt < 2; ++mt)
#pragma unroll
            for (int nt = 0; nt < 2; ++nt)
#pragma unroll
                for (int reg = 0; reg < 4; ++reg) {
                    int row = wm + mt * 16 + quad * 4 + reg;
                    int col = wn + nt * 16 + m16;
                    base[p * 4096 + row * 64 + col] = acc[p][mt][nt][reg];
                }
}

// ---------------------------------------------------------------------------
// Fat kernel L2: kv_reduce (blocks 0..2047, BW-bound) overlapped with
// band_select (blocks 2048..2111, latency-bound radix select).
// ---------------------------------------------------------------------------
__global__ __launch_bounds__(256) void select_reduce_kernel(
    const float* __restrict__ kvp, float* __restrict__ kv,
    const float* __restrict__ scores, int* __restrict__ selidx,
    int* __restrict__ band, int* __restrict__ meta)
{
    __shared__ unsigned keys[4096];
    __shared__ unsigned hist[256];
    __shared__ unsigned wtot[4];
    __shared__ unsigned bcast[2];
    __shared__ int cnt_in, cnt_band;

    int t = threadIdx.x;

    if (blockIdx.x < 2048) {
        // -------- kv_reduce: 16 partials -> kv --------
        int i = blockIdx.x * 256 + t;
        int bh = i >> 13;
        int rem = i & 8191;
        const float* p = kvp + (size_t)bh * 16 * 8192 + rem;
        float a = 0.f;
#pragma unroll
        for (int c = 0; c < 16; c++) a += p[c * 8192];
        kv[i] = a;
        return;
    }

    // -------- band_select (R5-proven wave-scan body) --------
    int bh = blockIdx.x - 2048;
    int wave = t >> 6, lane = t & 63;
    const float* sc = scores + (size_t)bh * S_;

    for (int i = t; i < 4096; i += 256) {
        unsigned u = __float_as_uint(sc[i]);
        u = (u & 0x80000000u) ? ~u : (u | 0x80000000u);
        keys[i] = u;
    }
    if (t == 0) { cnt_in = 0; cnt_band = 0; }

    unsigned prefix = 0, want = NS_;
    for (int shift = 24; shift >= 0; shift -= 8) {
        hist[t] = 0;
        __syncthreads();
        unsigned pmask = (shift == 24) ? 0u : (0xFFFFFFFFu << (shift + 8));
        for (int i = t; i < 4096; i += 256) {
            unsigned ky = keys[i];
            if ((ky & pmask) == prefix) atomicAdd(&hist[(ky >> shift) & 255u], 1u);
        }
        __syncthreads();
        unsigned sv = hist[t];
#pragma unroll
        for (int off = 1; off < 64; off <<= 1) {
            unsigned o = __shfl_down(sv, off, 64);
            sv += (lane + off < 64) ? o : 0u;
        }
        if (lane == 0) wtot[wave] = sv;
        __syncthreads();
        unsigned cross = 0;
#pragma unroll
        for (int w2 = 0; w2 < 4; ++w2)
            cross += (w2 > wave) ? wtot[w2] : 0u;
        unsigned Sb = sv + cross;
        unsigned sv1 = __shfl_down(sv, 1, 64);
        unsigned Snx = (lane < 63) ? sv1 + cross : cross;
        if (Sb >= want && Snx < want) {
            bcast[0] = (unsigned)t;
            bcast[1] = want - Snx;
        }
        __syncthreads();
        prefix = prefix | (bcast[0] << shift);
        want = bcast[1];
        __syncthreads();
    }
    unsigned fb = (prefix & 0x80000000u) ? (prefix ^ 0x80000000u) : ~prefix;
    float Ta = __uint_as_float(fb);
    float Thi = Ta + DELTA, Tlo = Ta - DELTA;

    int* sel = selidx + (size_t)bh * NS_;
    int* bnd = band + (size_t)bh * BANDCAP;
    for (int i = t; i < 4096; i += 256) {
        float v = sc[i];
        if (v > Thi) {
            int p = atomicAdd(&cnt_in, 1);
            sel[p] = i;
        } else if (v >= Tlo) {
            int p = atomicAdd(&cnt_band, 1);
            if (p < BANDCAP) bnd[p] = i;
        }
    }
    __syncthreads();
    if (t == 0) {
        meta[bh * 2 + 0] = cnt_in;
        meta[bh * 2 + 1] = (cnt_band < BANDCAP) ? cnt_band : BANDCAP;
    }
}

// ---------------------------------------------------------------------------
// Kernel 4: exact fp64 band rescoring, 4 independent fp64 accumulators.
// ---------------------------------------------------------------------------
__global__ __launch_bounds__(512) void band_exact_kernel(
    const float* __restrict__ x,
    const float* __restrict__ Wq, const float* __restrict__ Wk,
    const int* __restrict__ band, const int* __restrict__ meta,
    double* __restrict__ bscore)
{
    int j = blockIdx.x, bh = blockIdx.y;
    int NB = meta[bh * 2 + 1];
    if (j >= NB) return;
    int b = bh >> 4, h = bh & 15;
    int s = band[(size_t)bh * BANDCAP + j];
    int t = threadIdx.x;
    int wave = t >> 6, lane = t & 63;

    __shared__ float xs[1024];
    __shared__ double qkd[128];     // [0:64)=q dots, [64:128)=k dots

    if (t < 256)
        *(float4*)&xs[t * 4] = *(const float4*)(x + (size_t)(b * S_ + s) * K_ + t * 4);
    __syncthreads();

    const float* Wbase = (wave < 4) ? Wq : Wk;
    int role = wave >> 2;
    int dbase = (wave & 3) * 16;
    const float4* xs4 = (const float4*)xs;

    for (int rr = 0; rr < 16; ++rr) {
        int d = dbase + rr;
        const float4* wrow4 = (const float4*)(Wbase + (size_t)(h * 64 + d) * K_);
        double a0 = 0.0, a1 = 0.0, a2 = 0.0, a3 = 0.0;
#pragma unroll
        for (int p = 0; p < 4; ++p) {
            float4 wv = wrow4[lane + 64 * p];
            float4 xv = xs4[lane + 64 * p];
            a0 += (double)xv.x * wv.x;
            a1 += (double)xv.y * wv.y;
            a2 += (double)xv.z * wv.z;
            a3 += (double)xv.w * wv.w;
        }
        double a = (a0 + a1) + (a2 + a3);
#pragma unroll
        for (int m = 32; m; m >>= 1) a += __shfl_xor(a, m, 64);
        if (lane == 0) qkd[role * 64 + d] = a;
    }
    __syncthreads();

    if (t < 64) {
        double p = qkd[t] * qkd[64 + t];
#pragma unroll
        for (int m = 32; m; m >>= 1) p += __shfl_xor(p, m, 64);
        if (t == 0) bscore[(size_t)bh * BANDCAP + j] = p;
    }
}

// Kernel 5: rank band tokens (ties -> lower index), fill selidx positions.
__global__ __launch_bounds__(128) void band_rank_kernel(
    const double* __restrict__ bscore, const int* __restrict__ band,
    const int* __restrict__ meta, int* __restrict__ selidx)
{
    __shared__ double sc[BANDCAP];
    __shared__ int bi[BANDCAP];
    int bh = blockIdx.x, t = threadIdx.x;
    int cnt_in = meta[bh * 2 + 0], NB = meta[bh * 2 + 1];
    int need = NS_ - cnt_in;
    if (t < NB) {
        sc[t] = bscore[(size_t)bh * BANDCAP + t];
        bi[t] = band[(size_t)bh * BANDCAP + t];
    }
    __syncthreads();
    if (t < NB) {
        double mine = sc[t]; int myi = bi[t]; int r = 0;
        for (int j2 = 0; j2 < NB; ++j2)
            r += (sc[j2] > mine) || (sc[j2] == mine && bi[j2] < myi);
        if (r < need) selidx[(size_t)bh * NS_ + cnt_in + r] = myi;
    }
}

// ---------------------------------------------------------------------------
// Kernel 8: sampled = qs_cos @ kv_cos + qs_sin @ kv_sin, scattered to out.
// ---------------------------------------------------------------------------
__global__ __launch_bounds__(256) void sampled_kernel(
    const float* __restrict__ q32, const int* __restrict__ selidx,
    const float* __restrict__ kv, float* __restrict__ out)
{
    __shared__ __align__(16) float kvc[4096];
    __shared__ __align__(16) float kvs[4096];
    __shared__ __align__(16) float qs[64 * 68];   // stride 68: 16B-aligned rows
    __shared__ int sidx[64];
    int bh = blockIdx.y;
    int b = bh >> 4, h = bh & 15;
    int t = threadIdx.x;

    const float4* kvsrc4 = (const float4*)(kv + (size_t)bh * 8192);
    float4* kvc4 = (float4*)kvc;
    float4* kvs4 = (float4*)kvs;
#pragma unroll
    for (int i = 0; i < 4; ++i) {
        kvc4[i * 256 + t] = kvsrc4[i * 256 + t];
        kvs4[i * 256 + t] = kvsrc4[1024 + i * 256 + t];
    }
    if (t < 64) sidx[t] = selidx[(size_t)bh * NS_ + blockIdx.x * 64 + t];
    __syncthreads();

#pragma unroll
    for (int c = 0; c < 4; ++c) {
        int i = c * 256 + t;
        int row = i >> 4, qp = i & 15;
        int sr = sidx[row];
        *(float4*)&qs[row * 68 + qp * 4] =
            *(const float4*)(q32 + (size_t)(b * S_ + sr) * E_ + h * 64 + qp * 4);
    }
    __syncthreads();

    int tok = t >> 2, eq = t & 3;
    int sr = sidx[tok];
    float th = (float)sr * THSTEP;
    float cw = __cosf(th), sw = __sinf(th);

    f32x2 acc2[8];
#pragma unroll
    for (int e = 0; e < 8; e++) acc2[e] = (f32x2){0.f, 0.f};

    const float4* kvcb = (const float4*)&kvc[eq * 16];
    const float4* kvsb = (const float4*)&kvs[eq * 16];
    for (int d = 0; d < 64; ++d) {
        float qd = fmaxf(qs[tok * 68 + d], 0.f);
        f32x2 a2 = { qd * cw, qd * cw };
        f32x2 b2 = { qd * sw, qd * sw };
#pragma unroll
        for (int c = 0; c < 4; ++c) {
            float4 c4 = kvcb[d * 16 + c];
            float4 s4 = kvsb[d * 16 + c];
            f32x2 c01 = { c4.x, c4.y }, c23 = { c4.z, c4.w };
            f32x2 s01 = { s4.x, s4.y }, s23 = { s4.z, s4.w };
            acc2[c * 2 + 0] += a2 * c01 + b2 * s01;
            acc2[c * 2 + 1] += a2 * c23 + b2 * s23;
        }
    }

    float* dst = out + (size_t)(b * S_ + sr) * E_ + h * 64 + eq * 16;
#pragma unroll
    for (int c = 0; c < 4; ++c) {
        float4 o = { acc2[c * 2 + 0][0], acc2[c * 2 + 0][1],
                     acc2[c * 2 + 1][0], acc2[c * 2 + 1][1] };
        *(float4*)(dst + c * 4) = o;
    }
}

extern "C" void kernel_launch(void* const* d_in, const int* in_sizes, int n_in,
                              void* d_out, int out_size, void* d_ws, size_t ws_size,
                              hipStream_t stream)
{
    const float* x  = (const float*)d_in[0];
    const float* Wq = (const float*)d_in[1];
    const float* bq = (const float*)d_in[2];
    const float* Wk = (const float*)d_in[3];
    const float* bk = (const float*)d_in[4];
    const float* Wv = (const float*)d_in[5];
    const float* bv = (const float*)d_in[6];

    char* ws = (char*)d_ws;
    ushort* xh     = (ushort*)(ws);                   // 33,554,432 B
    float*  kvp    = (float*)(ws);                    // aliases xh (dead after GEMM)
    float*  q32    = (float*)(ws + 33554432);         // 67,108,864 B
    float*  k32    = (float*)(ws + 100663296);        // 67,108,864 B
    ushort* v16    = (ushort*)(ws + 167772160);       // 33,554,432 B
    ushort* Wqh    = (ushort*)(ws + 201326592);       //  2,097,152 B
    ushort* Wql    = (ushort*)(ws + 203423744);
    ushort* Wkh    = (ushort*)(ws + 205520896);
    ushort* Wkl    = (ushort*)(ws + 207618048);
    ushort* Wvh    = (ushort*)(ws + 209715200);
    float*  scores = (float*)(ws + 211812352);        //  1,048,576 B
    int*    selidx = (int*)(ws + 212860928);          //    262,144 B
    int*    band   = (int*)(ws + 213123072);          //     24,576 B
    double* bscore = (double*)(ws + 213147648);       //     49,152 B
    int*    meta   = (int*)(ws + 213196800);          //        512 B
    float*  kv     = (float*)(ws + 213197312);        //  2,097,152 B (end ~205.3 MiB)
    float*  out    = (float*)d_out;

    hipLaunchKernelGGL(prep_kernel, dim3(4096), dim3(256), 0, stream,
                       x, Wq, Wk, Wv, xh, Wqh, Wql, Wkh, Wkl, Wvh, (uint4*)out);
    hipLaunchKernelGGL(qkv_gemm, dim3(128, 8, 3), dim3(256), 0, stream,
                       xh, Wqh, Wql, Wkh, Wkl, Wvh, bq, bk, bv, q32, k32, v16);
    hipLaunchKernelGGL(scores_kv_kernel, dim3(1024 + 16384), dim3(256), 0, stream,
                       q32, k32, v16, scores, kvp);
    hipLaunchKernelGGL(select_reduce_kernel, dim3(2048 + 64), dim3(256), 0, stream,
                       kvp, kv, scores, selidx, band, meta);
    hipLaunchKernelGGL(band_exact_kernel, dim3(BANDCAP, B_ * H_), dim3(512), 0, stream,
                       x, Wq, Wk, band, meta, bscore);
    hipLaunchKernelGGL(band_rank_kernel, dim3(B_ * H_), dim3(128), 0, stream,
                       bscore, band, meta, selidx);
    hipLaunchKernelGGL(sampled_kernel, dim3(NS_ / 64, B_ * H_), dim3(256), 0, stream,
                       q32, selidx, kv, out);
}

// Round 8
// 477.137 us; speedup vs baseline: 1.0760x; 1.0760x over previous
//
#include <hip/hip_runtime.h>
#include <hip/hip_bf16.h>

#define B_ 4
#define S_ 4096
#define E_ 1024
#define H_ 16
#define D_ 64
#define NS_ 1024
#define M_ (B_*S_)
#define K_ E_
#define DELTA 0.12f
#define BANDCAP 96

typedef __attribute__((ext_vector_type(8))) short bf16x8;
typedef __attribute__((ext_vector_type(4))) float floatx4;
typedef __attribute__((ext_vector_type(2))) float f32x2;

#define THSTEP 0.00038349519697141023f  /* (pi/2)/4096 */

__device__ inline float bf16_to_f(unsigned short u) {
    return __uint_as_float(((unsigned)u) << 16);
}
__device__ inline unsigned short f_to_bf16(float f) {
    unsigned u = __float_as_uint(f);
    unsigned r = (u + 0x7FFFu + ((u >> 16) & 1u)) >> 16;  // RNE
    return (unsigned short)r;
}

// async global->LDS DMA, 16B per lane, wave-uniform LDS base + lane*16 dest.
__device__ inline void gl_lds16(const void* g, void* l) {
    __builtin_amdgcn_global_load_lds(
        (const __attribute__((address_space(1))) void*)g,
        (__attribute__((address_space(3))) void*)l, 16, 0, 0);
}

// ---------------------------------------------------------------------------
// Prep kernel: fuses {zero(out), x->xh bf16, W splits}.  4096 blocks x 256.
// ---------------------------------------------------------------------------
__global__ __launch_bounds__(256) void prep_kernel(
    const float* __restrict__ x,
    const float* __restrict__ Wq, const float* __restrict__ Wk,
    const float* __restrict__ Wv,
    ushort* __restrict__ xh,
    ushort* __restrict__ Wqh, ushort* __restrict__ Wql,
    ushort* __restrict__ Wkh, ushort* __restrict__ Wkl,
    ushort* __restrict__ Wvh,
    uint4* __restrict__ outz)
{
    int t = blockIdx.x * 256 + threadIdx.x;     // 0 .. 1,048,575
    uint4 z = make_uint4(0u, 0u, 0u, 0u);
#pragma unroll
    for (int c = 0; c < 4; ++c)
        outz[c * 1048576 + t] = z;               // 4M uint4 = 64MB out
#pragma unroll
    for (int c = 0; c < 4; ++c) {
        int i = c * 1048576 + t;                 // 4M float4 of x
        float4 v = ((const float4*)x)[i];
        ushort4 hh;
        hh.x = f_to_bf16(v.x); hh.y = f_to_bf16(v.y);
        hh.z = f_to_bf16(v.z); hh.w = f_to_bf16(v.w);
        ((ushort4*)xh)[i] = hh;
    }
    if (t < 262144) {                            // 256K float4 per W matrix
        int i = t;
        float4 q = ((const float4*)Wq)[i];
        float4 k = ((const float4*)Wk)[i];
        float4 v = ((const float4*)Wv)[i];
        ushort4 h, l;
        h.x=f_to_bf16(q.x); l.x=f_to_bf16(q.x-bf16_to_f(h.x));
        h.y=f_to_bf16(q.y); l.y=f_to_bf16(q.y-bf16_to_f(h.y));
        h.z=f_to_bf16(q.z); l.z=f_to_bf16(q.z-bf16_to_f(h.z));
        h.w=f_to_bf16(q.w); l.w=f_to_bf16(q.w-bf16_to_f(h.w));
        ((ushort4*)Wqh)[i]=h; ((ushort4*)Wql)[i]=l;
        h.x=f_to_bf16(k.x); l.x=f_to_bf16(k.x-bf16_to_f(h.x));
        h.y=f_to_bf16(k.y); l.y=f_to_bf16(k.y-bf16_to_f(h.y));
        h.z=f_to_bf16(k.z); l.z=f_to_bf16(k.z-bf16_to_f(h.z));
        h.w=f_to_bf16(k.w); l.w=f_to_bf16(k.w-bf16_to_f(h.w));
        ((ushort4*)Wkh)[i]=h; ((ushort4*)Wkl)[i]=l;
        h.x=f_to_bf16(v.x); h.y=f_to_bf16(v.y);
        h.z=f_to_bf16(v.z); h.w=f_to_bf16(v.w);
        ((ushort4*)Wvh)[i]=h;
    }
}

// ---------------------------------------------------------------------------
// Kernel 1: QKV GEMM — R1/R5 proven form (149-150 µs, MfmaUtil 53%), FROZEN.
// merged z=3, global_load_lds width-16, XCD-grouped grid, BK=64, 2 barriers
// per K-step.  2-phase BK=32 variant measured 185 µs (R7) — do not reapply.
// ---------------------------------------------------------------------------
__global__ __launch_bounds__(256) void qkv_gemm(
    const ushort* __restrict__ xh,
    const ushort* __restrict__ Wqh, const ushort* __restrict__ Wql,
    const ushort* __restrict__ Wkh, const ushort* __restrict__ Wkl,
    const ushort* __restrict__ Wvh,
    const float* __restrict__ bq, const float* __restrict__ bk,
    const float* __restrict__ bv,
    float* __restrict__ q32, float* __restrict__ k32, ushort* __restrict__ v16)
{
    __shared__ __align__(16) ushort As[128 * 64];
    __shared__ __align__(16) ushort Bsh[128 * 64];
    __shared__ __align__(16) ushort Bsl[128 * 64];

    const int w = blockIdx.z;
    const ushort* Bhp = (w == 0) ? Wqh : (w == 1) ? Wkh : Wvh;
    const ushort* Blp = (w == 0) ? Wql : Wkl;      // unused when w==2
    const float* bias = (w == 0) ? bq : (w == 1) ? bk : bv;
    const bool lo = (w < 2);

    const int m0 = blockIdx.x * 128;
    const int n0 = blockIdx.y * 128;
    const int t = threadIdx.x;
    const int wave = t >> 6, lane = t & 63;
    const int wm = (wave >> 1) * 64, wn = (wave & 1) * 64;
    const int m16 = lane & 15, quad = lane >> 4;

    floatx4 acc[4][4];
#pragma unroll
    for (int i = 0; i < 4; i++)
#pragma unroll
        for (int j = 0; j < 4; j++) acc[i][j] = (floatx4){0.f, 0.f, 0.f, 0.f};

    int aoff[4], boff[4], lbase[4];
#pragma unroll
    for (int i = 0; i < 4; i++) {
        int slot = i * 256 + t;
        int r = slot >> 3, c = slot & 7, g = c ^ (r & 7);
        aoff[i] = (m0 + r) * K_ + g * 8;
        boff[i] = (n0 + r) * K_ + g * 8;
        lbase[i] = (i * 256 + wave * 64) * 8;   // wave-uniform LDS element base
    }

    for (int ks = 0; ks < 16; ++ks) {
        const int kcol = ks * 64;
#pragma unroll
        for (int i = 0; i < 4; i++) {
            gl_lds16(xh + aoff[i] + kcol, &As[lbase[i]]);
            gl_lds16(Bhp + boff[i] + kcol, &Bsh[lbase[i]]);
        }
        if (lo) {
#pragma unroll
            for (int i = 0; i < 4; i++)
                gl_lds16(Blp + boff[i] + kcol, &Bsl[lbase[i]]);
        }
        __syncthreads();

#pragma unroll
        for (int kk = 0; kk < 2; ++kk) {
            bf16x8 af[4], bfr[4];
            const int g = kk * 4 + quad;
#pragma unroll
            for (int mt = 0; mt < 4; ++mt) {
                int r = wm + mt * 16 + m16;
                af[mt] = *(const bf16x8*)&As[(r * 8 + (g ^ (r & 7))) * 8];
            }
#pragma unroll
            for (int nt = 0; nt < 4; ++nt) {
                int r2 = wn + nt * 16 + m16;
                bfr[nt] = *(const bf16x8*)&Bsh[(r2 * 8 + (g ^ (r2 & 7))) * 8];
            }
#pragma unroll
            for (int mt = 0; mt < 4; ++mt)
#pragma unroll
                for (int nt = 0; nt < 4; ++nt)
                    acc[mt][nt] = __builtin_amdgcn_mfma_f32_16x16x32_bf16(
                        af[mt], bfr[nt], acc[mt][nt], 0, 0, 0);
            if (lo) {
#pragma unroll
                for (int nt = 0; nt < 4; ++nt) {
                    int r2 = wn + nt * 16 + m16;
                    bfr[nt] = *(const bf16x8*)&Bsl[(r2 * 8 + (g ^ (r2 & 7))) * 8];
                }
#pragma unroll
                for (int mt = 0; mt < 4; ++mt)
#pragma unroll
                    for (int nt = 0; nt < 4; ++nt)
                        acc[mt][nt] = __builtin_amdgcn_mfma_f32_16x16x32_bf16(
                            af[mt], bfr[nt], acc[mt][nt], 0, 0, 0);
            }
        }
        __syncthreads();
    }

    float biasv[4];
#pragma unroll
    for (int nt = 0; nt < 4; nt++)
        biasv[nt] = bias[n0 + wn + nt * 16 + m16];

    if (w < 2) {
        float* dst = (w == 0) ? q32 : k32;
#pragma unroll
        for (int mt = 0; mt < 4; ++mt)
#pragma unroll
            for (int nt = 0; nt < 4; ++nt) {
                int colg = n0 + wn + nt * 16 + m16;
#pragma unroll
                for (int reg = 0; reg < 4; ++reg) {
                    int rowg = m0 + wm + mt * 16 + quad * 4 + reg;
                    dst[(size_t)rowg * E_ + colg] = acc[mt][nt][reg] + biasv[nt];
                }
            }
    } else {
#pragma unroll
        for (int mt = 0; mt < 4; ++mt)
#pragma unroll
            for (int nt = 0; nt < 4; ++nt) {
                int colg = n0 + wn + nt * 16 + m16;
#pragma unroll
                for (int reg = 0; reg < 4; ++reg) {
                    int rowg = m0 + wm + mt * 16 + quad * 4 + reg;
                    v16[(size_t)rowg * E_ + colg] = f_to_bf16(acc[mt][nt][reg] + biasv[nt]);
                }
            }
    }
}

// ---------------------------------------------------------------------------
// Fat kernel L1: kv_mfma (blocks 0..1023, MFMA/VALU-bound) overlapped with
// scores (blocks 1024..17407, BW-bound, 16 tokens/block).
// ---------------------------------------------------------------------------
__global__ __launch_bounds__(256) void scores_kv_kernel(
    const float* __restrict__ q32, const float* __restrict__ k32,
    const ushort* __restrict__ v16,
    float* __restrict__ scores, float* __restrict__ kvp)
{
    // planes: 0 kc_hi, 1 kc_lo, 2 ks_hi, 3 ks_lo, 4 v   (each [64][88] ushort)
    __shared__ __align__(16) ushort P[5 * 64 * 88];
    const int t = threadIdx.x;

    if (blockIdx.x >= 1024) {
        // ---------------- scores: sum_d q*k, one token per 16-lane group ----
        int g = (blockIdx.x - 1024) * 16 + (t >> 4);
        int sub = t & 15;
        int s = g & (S_ - 1);
        int bh = g >> 12;
        int b = bh >> 4, h = bh & 15;
        size_t addr = (size_t)(b * S_ + s) * E_ + h * 64 + sub * 4;
        float4 qv = *(const float4*)(q32 + addr);
        float4 kv = *(const float4*)(k32 + addr);
        float p = qv.x * kv.x + qv.y * kv.y + qv.z * kv.z + qv.w * kv.w;
#pragma unroll
        for (int m = 8; m; m >>= 1) p += __shfl_xor(p, m, 64);
        if (sub == 0) scores[g] = p;
        return;
    }

    // ---------------- kv_mfma (R4-proven body) -----------------------------
    const int ch = blockIdx.x & 15;
    const int bh = blockIdx.x >> 4;
    const int b = bh >> 4, h = bh & 15;
    const int wave = t >> 6, lane = t & 63;
    const int m16 = lane & 15, quad = lane >> 4;
    const int wm = (wave >> 1) * 32, wn = (wave & 1) * 32;
    const int d0 = wave * 16;

    const float*  kbase = k32 + (size_t)b * S_ * E_ + h * 64 + d0;
    const ushort* vbase = v16 + (size_t)b * S_ * E_ + h * 64 + d0;

    floatx4 acc[2][2][2];
#pragma unroll
    for (int p = 0; p < 2; p++)
#pragma unroll
        for (int i = 0; i < 2; i++)
#pragma unroll
            for (int j = 0; j < 2; j++) acc[p][i][j] = (floatx4){0.f,0.f,0.f,0.f};

    float  ka[16];
    ushort va[16];
    int sg = ch * 256 + lane;
    {
        const float*  kr = kbase + (size_t)sg * E_;
        const ushort* vr = vbase + (size_t)sg * E_;
#pragma unroll
        for (int j = 0; j < 4; ++j) *(float4*)&ka[j * 4] = ((const float4*)kr)[j];
        *(uint4*)&va[0] = *(const uint4*)vr;
        *(uint4*)&va[8] = *(const uint4*)(vr + 8);
    }

    for (int grp = 0; grp < 4; ++grp) {
        float th = (float)sg * THSTEP;
        float cw = __cosf(th), sw = __sinf(th);
        int s_loc = lane;

        __syncthreads();
#pragma unroll
        for (int j = 0; j < 16; ++j) {
            float kr_ = fmaxf(ka[j], 0.f);
            float pc = kr_ * cw, ps = kr_ * sw;
            ushort chh = f_to_bf16(pc);
            ushort cll = f_to_bf16(pc - bf16_to_f(chh));
            ushort shh = f_to_bf16(ps);
            ushort sll = f_to_bf16(ps - bf16_to_f(shh));
            int r = (d0 + j) * 88 + s_loc;
            P[0 * 5632 + r] = chh;
            P[1 * 5632 + r] = cll;
            P[2 * 5632 + r] = shh;
            P[3 * 5632 + r] = sll;
            P[4 * 5632 + r] = va[j];
        }
        __syncthreads();

        if (grp < 3) {
            sg += 64;
            const float*  kr = kbase + (size_t)sg * E_;
            const ushort* vr = vbase + (size_t)sg * E_;
#pragma unroll
            for (int j = 0; j < 4; ++j) *(float4*)&ka[j * 4] = ((const float4*)kr)[j];
            *(uint4*)&va[0] = *(const uint4*)vr;
            *(uint4*)&va[8] = *(const uint4*)(vr + 8);
        }

#pragma unroll
        for (int kk = 0; kk < 2; ++kk) {
            const int so = kk * 32 + quad * 8;
            bf16x8 ach[2], acl[2], ash[2], asl[2], bv[2];
#pragma unroll
            for (int mt = 0; mt < 2; ++mt) {
                int r = (wm + mt * 16 + m16) * 88 + so;
                ach[mt] = *(const bf16x8*)&P[0 * 5632 + r];
                acl[mt] = *(const bf16x8*)&P[1 * 5632 + r];
                ash[mt] = *(const bf16x8*)&P[2 * 5632 + r];
                asl[mt] = *(const bf16x8*)&P[3 * 5632 + r];
            }
#pragma unroll
            for (int nt = 0; nt < 2; ++nt) {
                int r = (wn + nt * 16 + m16) * 88 + so;
                bv[nt] = *(const bf16x8*)&P[4 * 5632 + r];
            }
#pragma unroll
            for (int mt = 0; mt < 2; ++mt)
#pragma unroll
                for (int nt = 0; nt < 2; ++nt) {
                    acc[0][mt][nt] = __builtin_amdgcn_mfma_f32_16x16x32_bf16(
                        ach[mt], bv[nt], acc[0][mt][nt], 0, 0, 0);
                    acc[0][mt][nt] = __builtin_amdgcn_mfma_f32_16x16x32_bf16(
                        acl[mt], bv[nt], acc[0][mt][nt], 0, 0, 0);
                    acc[1][mt][nt] = __builtin_amdgcn_mfma_f32_16x16x32_bf16(
                        ash[mt], bv[nt], acc[1][mt][nt], 0, 0, 0);
                    acc[1][mt][nt] = __builtin_amdgcn_mfma_f32_16x16x32_bf16(
                        asl[mt], bv[nt], acc[1][mt][nt], 0, 0, 0);
                }
        }
    }

    float* base = kvp + ((size_t)(bh * 16 + ch) * 2) * 4096;
#pragma unroll
    for (int p = 0; p < 2; ++p)
#pragma unroll
        for (int mt = 0; mt < 2; ++mt)
#pragma unroll
            for (int nt = 0; nt < 2; ++nt)
#pragma unroll
                for (int reg = 0; reg < 4; ++reg) {
                    int row = wm + mt * 16 + quad * 4 + reg;
                    int col = wn + nt * 16 + m16;
                    base[p * 4096 + row * 64 + col] = acc[p][mt][nt][reg];
                }
}

// ---------------------------------------------------------------------------
// Fat kernel L2: kv_reduce (blocks 0..2047, BW-bound) overlapped with
// band_select (blocks 2048..2111, latency-bound radix select).
// ---------------------------------------------------------------------------
__global__ __launch_bounds__(256) void select_reduce_kernel(
    const float* __restrict__ kvp, float* __restrict__ kv,
    const float* __restrict__ scores, int* __restrict__ selidx,
    int* __restrict__ band, int* __restrict__ meta)
{
    __shared__ unsigned keys[4096];
    __shared__ unsigned hist[256];
    __shared__ unsigned wtot[4];
    __shared__ unsigned bcast[2];
    __shared__ int cnt_in, cnt_band;

    int t = threadIdx.x;

    if (blockIdx.x < 2048) {
        // -------- kv_reduce: 16 partials -> kv --------
        int i = blockIdx.x * 256 + t;
        int bh = i >> 13;
        int rem = i & 8191;
        const float* p = kvp + (size_t)bh * 16 * 8192 + rem;
        float a = 0.f;
#pragma unroll
        for (int c = 0; c < 16; c++) a += p[c * 8192];
        kv[i] = a;
        return;
    }

    // -------- band_select (R5-proven wave-scan body) --------
    int bh = blockIdx.x - 2048;
    int wave = t >> 6, lane = t & 63;
    const float* sc = scores + (size_t)bh * S_;

    for (int i = t; i < 4096; i += 256) {
        unsigned u = __float_as_uint(sc[i]);
        u = (u & 0x80000000u) ? ~u : (u | 0x80000000u);
        keys[i] = u;
    }
    if (t == 0) { cnt_in = 0; cnt_band = 0; }

    unsigned prefix = 0, want = NS_;
    for (int shift = 24; shift >= 0; shift -= 8) {
        hist[t] = 0;
        __syncthreads();
        unsigned pmask = (shift == 24) ? 0u : (0xFFFFFFFFu << (shift + 8));
        for (int i = t; i < 4096; i += 256) {
            unsigned ky = keys[i];
            if ((ky & pmask) == prefix) atomicAdd(&hist[(ky >> shift) & 255u], 1u);
        }
        __syncthreads();
        unsigned sv = hist[t];
#pragma unroll
        for (int off = 1; off < 64; off <<= 1) {
            unsigned o = __shfl_down(sv, off, 64);
            sv += (lane + off < 64) ? o : 0u;
        }
        if (lane == 0) wtot[wave] = sv;
        __syncthreads();
        unsigned cross = 0;
#pragma unroll
        for (int w2 = 0; w2 < 4; ++w2)
            cross += (w2 > wave) ? wtot[w2] : 0u;
        unsigned Sb = sv + cross;
        unsigned sv1 = __shfl_down(sv, 1, 64);
        unsigned Snx = (lane < 63) ? sv1 + cross : cross;
        if (Sb >= want && Snx < want) {
            bcast[0] = (unsigned)t;
            bcast[1] = want - Snx;
        }
        __syncthreads();
        prefix = prefix | (bcast[0] << shift);
        want = bcast[1];
        __syncthreads();
    }
    unsigned fb = (prefix & 0x80000000u) ? (prefix ^ 0x80000000u) : ~prefix;
    float Ta = __uint_as_float(fb);
    float Thi = Ta + DELTA, Tlo = Ta - DELTA;

    int* sel = selidx + (size_t)bh * NS_;
    int* bnd = band + (size_t)bh * BANDCAP;
    for (int i = t; i < 4096; i += 256) {
        float v = sc[i];
        if (v > Thi) {
            int p = atomicAdd(&cnt_in, 1);
            sel[p] = i;
        } else if (v >= Tlo) {
            int p = atomicAdd(&cnt_band, 1);
            if (p < BANDCAP) bnd[p] = i;
        }
    }
    __syncthreads();
    if (t == 0) {
        meta[bh * 2 + 0] = cnt_in;
        meta[bh * 2 + 1] = (cnt_band < BANDCAP) ? cnt_band : BANDCAP;
    }
}

// ---------------------------------------------------------------------------
// Kernel 4: exact fp64 band rescoring, 4 independent fp64 accumulators.
// ---------------------------------------------------------------------------
__global__ __launch_bounds__(512) void band_exact_kernel(
    const float* __restrict__ x,
    const float* __restrict__ Wq, const float* __restrict__ Wk,
    const int* __restrict__ band, const int* __restrict__ meta,
    double* __restrict__ bscore)
{
    int j = blockIdx.x, bh = blockIdx.y;
    int NB = meta[bh * 2 + 1];
    if (j >= NB) return;
    int b = bh >> 4, h = bh & 15;
    int s = band[(size_t)bh * BANDCAP + j];
    int t = threadIdx.x;
    int wave = t >> 6, lane = t & 63;

    __shared__ float xs[1024];
    __shared__ double qkd[128];     // [0:64)=q dots, [64:128)=k dots

    if (t < 256)
        *(float4*)&xs[t * 4] = *(const float4*)(x + (size_t)(b * S_ + s) * K_ + t * 4);
    __syncthreads();

    const float* Wbase = (wave < 4) ? Wq : Wk;
    int role = wave >> 2;
    int dbase = (wave & 3) * 16;
    const float4* xs4 = (const float4*)xs;

    for (int rr = 0; rr < 16; ++rr) {
        int d = dbase + rr;
        const float4* wrow4 = (const float4*)(Wbase + (size_t)(h * 64 + d) * K_);
        double a0 = 0.0, a1 = 0.0, a2 = 0.0, a3 = 0.0;
#pragma unroll
        for (int p = 0; p < 4; ++p) {
            float4 wv = wrow4[lane + 64 * p];
            float4 xv = xs4[lane + 64 * p];
            a0 += (double)xv.x * wv.x;
            a1 += (double)xv.y * wv.y;
            a2 += (double)xv.z * wv.z;
            a3 += (double)xv.w * wv.w;
        }
        double a = (a0 + a1) + (a2 + a3);
#pragma unroll
        for (int m = 32; m; m >>= 1) a += __shfl_xor(a, m, 64);
        if (lane == 0) qkd[role * 64 + d] = a;
    }
    __syncthreads();

    if (t < 64) {
        double p = qkd[t] * qkd[64 + t];
#pragma unroll
        for (int m = 32; m; m >>= 1) p += __shfl_xor(p, m, 64);
        if (t == 0) bscore[(size_t)bh * BANDCAP + j] = p;
    }
}

// Kernel 5: rank band tokens (ties -> lower index), fill selidx positions.
__global__ __launch_bounds__(128) void band_rank_kernel(
    const double* __restrict__ bscore, const int* __restrict__ band,
    const int* __restrict__ meta, int* __restrict__ selidx)
{
    __shared__ double sc[BANDCAP];
    __shared__ int bi[BANDCAP];
    int bh = blockIdx.x, t = threadIdx.x;
    int cnt_in = meta[bh * 2 + 0], NB = meta[bh * 2 + 1];
    int need = NS_ - cnt_in;
    if (t < NB) {
        sc[t] = bscore[(size_t)bh * BANDCAP + t];
        bi[t] = band[(size_t)bh * BANDCAP + t];
    }
    __syncthreads();
    if (t < NB) {
        double mine = sc[t]; int myi = bi[t]; int r = 0;
        for (int j2 = 0; j2 < NB; ++j2)
            r += (sc[j2] > mine) || (sc[j2] == mine && bi[j2] < myi);
        if (r < need) selidx[(size_t)bh * NS_ + cnt_in + r] = myi;
    }
}

// ---------------------------------------------------------------------------
// Kernel 8: sampled = qs_cos @ kv_cos + qs_sin @ kv_sin, scattered to out.
// ---------------------------------------------------------------------------
__global__ __launch_bounds__(256) void sampled_kernel(
    const float* __restrict__ q32, const int* __restrict__ selidx,
    const float* __restrict__ kv, float* __restrict__ out)
{
    __shared__ __align__(16) float kvc[4096];
    __shared__ __align__(16) float kvs[4096];
    __shared__ __align__(16) float qs[64 * 68];   // stride 68: 16B-aligned rows
    __shared__ int sidx[64];
    int bh = blockIdx.y;
    int b = bh >> 4, h = bh & 15;
    int t = threadIdx.x;

    const float4* kvsrc4 = (const float4*)(kv + (size_t)bh * 8192);
    float4* kvc4 = (float4*)kvc;
    float4* kvs4 = (float4*)kvs;
#pragma unroll
    for (int i = 0; i < 4; ++i) {
        kvc4[i * 256 + t] = kvsrc4[i * 256 + t];
        kvs4[i * 256 + t] = kvsrc4[1024 + i * 256 + t];
    }
    if (t < 64) sidx[t] = selidx[(size_t)bh * NS_ + blockIdx.x * 64 + t];
    __syncthreads();

#pragma unroll
    for (int c = 0; c < 4; ++c) {
        int i = c * 256 + t;
        int row = i >> 4, qp = i & 15;
        int sr = sidx[row];
        *(float4*)&qs[row * 68 + qp * 4] =
            *(const float4*)(q32 + (size_t)(b * S_ + sr) * E_ + h * 64 + qp * 4);
    }
    __syncthreads();

    int tok = t >> 2, eq = t & 3;
    int sr = sidx[tok];
    float th = (float)sr * THSTEP;
    float cw = __cosf(th), sw = __sinf(th);

    f32x2 acc2[8];
#pragma unroll
    for (int e = 0; e < 8; e++) acc2[e] = (f32x2){0.f, 0.f};

    const float4* kvcb = (const float4*)&kvc[eq * 16];
    const float4* kvsb = (const float4*)&kvs[eq * 16];
    for (int d = 0; d < 64; ++d) {
        float qd = fmaxf(qs[tok * 68 + d], 0.f);
        f32x2 a2 = { qd * cw, qd * cw };
        f32x2 b2 = { qd * sw, qd * sw };
#pragma unroll
        for (int c = 0; c < 4; ++c) {
            float4 c4 = kvcb[d * 16 + c];
            float4 s4 = kvsb[d * 16 + c];
            f32x2 c01 = { c4.x, c4.y }, c23 = { c4.z, c4.w };
            f32x2 s01 = { s4.x, s4.y }, s23 = { s4.z, s4.w };
            acc2[c * 2 + 0] += a2 * c01 + b2 * s01;
            acc2[c * 2 + 1] += a2 * c23 + b2 * s23;
        }
    }

    float* dst = out + (size_t)(b * S_ + sr) * E_ + h * 64 + eq * 16;
#pragma unroll
    for (int c = 0; c < 4; ++c) {
        float4 o = { acc2[c * 2 + 0][0], acc2[c * 2 + 0][1],
                     acc2[c * 2 + 1][0], acc2[c * 2 + 1][1] };
        *(float4*)(dst + c * 4) = o;
    }
}

extern "C" void kernel_launch(void* const* d_in, const int* in_sizes, int n_in,
                              void* d_out, int out_size, void* d_ws, size_t ws_size,
                              hipStream_t stream)
{
    const float* x  = (const float*)d_in[0];
    const float* Wq = (const float*)d_in[1];
    const float* bq = (const float*)d_in[2];
    const float* Wk = (const float*)d_in[3];
    const float* bk = (const float*)d_in[4];
    const float* Wv = (const float*)d_in[5];
    const float* bv = (const float*)d_in[6];

    char* ws = (char*)d_ws;
    ushort* xh     = (ushort*)(ws);                   // 33,554,432 B
    float*  kvp    = (float*)(ws);                    // aliases xh (dead after GEMM)
    float*  q32    = (float*)(ws + 33554432);         // 67,108,864 B
    float*  k32    = (float*)(ws + 100663296);        // 67,108,864 B
    ushort* v16    = (ushort*)(ws + 167772160);       // 33,554,432 B
    ushort* Wqh    = (ushort*)(ws + 201326592);       //  2,097,152 B
    ushort* Wql    = (ushort*)(ws + 203423744);
    ushort* Wkh    = (ushort*)(ws + 205520896);
    ushort* Wkl    = (ushort*)(ws + 207618048);
    ushort* Wvh    = (ushort*)(ws + 209715200);
    float*  scores = (float*)(ws + 211812352);        //  1,048,576 B
    int*    selidx = (int*)(ws + 212860928);          //    262,144 B
    int*    band   = (int*)(ws + 213123072);          //     24,576 B
    double* bscore = (double*)(ws + 213147648);       //     49,152 B
    int*    meta   = (int*)(ws + 213196800);          //        512 B
    float*  kv     = (float*)(ws + 213197312);        //  2,097,152 B (end ~205.3 MiB)
    float*  out    = (float*)d_out;

    hipLaunchKernelGGL(prep_kernel, dim3(4096), dim3(256), 0, stream,
                       x, Wq, Wk, Wv, xh, Wqh, Wql, Wkh, Wkl, Wvh, (uint4*)out);
    hipLaunchKernelGGL(qkv_gemm, dim3(128, 8, 3), dim3(256), 0, stream,
                       xh, Wqh, Wql, Wkh, Wkl, Wvh, bq, bk, bv, q32, k32, v16);
    hipLaunchKernelGGL(scores_kv_kernel, dim3(1024 + 16384), dim3(256), 0, stream,
                       q32, k32, v16, scores, kvp);
    hipLaunchKernelGGL(select_reduce_kernel, dim3(2048 + 64), dim3(256), 0, stream,
                       kvp, kv, scores, selidx, band, meta);
    hipLaunchKernelGGL(band_exact_kernel, dim3(BANDCAP, B_ * H_), dim3(512), 0, stream,
                       x, Wq, Wk, band, meta, bscore);
    hipLaunchKernelGGL(band_rank_kernel, dim3(B_ * H_), dim3(128), 0, stream,
                       bscore, band, meta, selidx);
    hipLaunchKernelGGL(sampled_kernel, dim3(NS_ / 64, B_ * H_), dim3(256), 0, stream,
                       q32, selidx, kv, out);
}